// Round 5
// baseline (354.840 us; speedup 1.0000x reference)
//
#include <hip/hip_runtime.h>

#define DCOLS 256
#define RB 128             // rows per bin
#define NBIN_PAD 1024      // padded bin count (actual 782)
#define PAIRS_OFF 16384    // byte offset of pairs[] in d_ws
#define SUB4 1024          // int4 per scatter block (4096 elements)
#define CAPC 17152u        // pairs capacity per bin (mean 16368 + ~6 sigma)
#define OVF_CAP (1u<<20)   // overflow list capacity (pairs)

typedef unsigned int u32;
typedef unsigned long long u64;

// ---------------- fallback path ----------------
__global__ void copy_f4(const float4* __restrict__ src, float4* __restrict__ dst, int n4) {
    int i = blockIdx.x * blockDim.x + threadIdx.x;
    int stride = gridDim.x * blockDim.x;
    for (; i < n4; i += stride) dst[i] = src[i];
}

__global__ void scatter_add4(const int4* __restrict__ index,
                             const float4* __restrict__ upd,
                             float* __restrict__ out, int n4) {
    int i = blockIdx.x * blockDim.x + threadIdx.x;
    int stride = gridDim.x * blockDim.x;
    for (; i < n4; i += stride) {
        int4 idx  = index[i];
        float4 u  = upd[i];
        int j = (i << 2) & (DCOLS - 1);
        atomicAdd(&out[idx.x * DCOLS + j + 0], u.x);
        atomicAdd(&out[idx.y * DCOLS + j + 1], u.y);
        atomicAdd(&out[idx.z * DCOLS + j + 2], u.z);
        atomicAdd(&out[idx.w * DCOLS + j + 3], u.w);
    }
}

// ---------------- meta init ----------------
// capacity mode: start/cursor = bin*C, ovf_cnt = 0
__global__ void zero_cap(u32* __restrict__ meta, u32 C) {
    int t = threadIdx.x;
    meta[1024 + t] = (u32)t * C;   // start
    meta[2048 + t] = (u32)t * C;   // cursor
    if (t == 0) meta[3072] = 0;    // ovf_cnt
}

// exact mode kernels
__global__ void zero_meta(u32* __restrict__ count, int nbins) {
    int i = threadIdx.x;
    if (i < nbins) count[i] = 0;
}

__global__ void __launch_bounds__(256) count_bins(const int4* __restrict__ idx4,
                                                  u32* __restrict__ count, int n4) {
    __shared__ u32 hist[NBIN_PAD];
    for (int i = threadIdx.x; i < NBIN_PAD; i += blockDim.x) hist[i] = 0;
    __syncthreads();
    int i = blockIdx.x * blockDim.x + threadIdx.x;
    int stride = gridDim.x * blockDim.x;
    for (; i < n4; i += stride) {
        int4 v = idx4[i];
        atomicAdd(&hist[((u32)v.x) >> 7], 1u);
        atomicAdd(&hist[((u32)v.y) >> 7], 1u);
        atomicAdd(&hist[((u32)v.z) >> 7], 1u);
        atomicAdd(&hist[((u32)v.w) >> 7], 1u);
    }
    __syncthreads();
    for (int i2 = threadIdx.x; i2 < NBIN_PAD; i2 += blockDim.x)
        if (hist[i2]) atomicAdd(&count[i2], hist[i2]);
}

__global__ void scan_bins(const u32* __restrict__ count, u32* __restrict__ start,
                          u32* __restrict__ cursor, int nbins) {
    __shared__ u32 tmp[1024];
    int t = threadIdx.x;
    u32 v = (t < nbins) ? count[t] : 0u;
    tmp[t] = v;
    __syncthreads();
    for (int off = 1; off < 1024; off <<= 1) {
        u32 a = 0;
        if (t >= off) a = tmp[t - off];
        __syncthreads();
        tmp[t] += a;
        __syncthreads();
    }
    if (t < nbins) {
        u32 excl = tmp[t] - v;
        start[t] = excl;
        cursor[t] = excl;
    }
}

// ---------------- scatter v4: one 4096-elem sub-chunk per block ----------------
// LDS = 4096 (hist) + 4096 (bme) + 32768 (stage) = 40960 B -> 4 blocks/CU.
// C==0 -> exact mode (no overflow possible); C>0 -> capacity mode.
__global__ void __launch_bounds__(256, 4) scatter_v4(const int4* __restrict__ idx4,
                                                     const float4* __restrict__ upd4,
                                                     u32* __restrict__ cursor,
                                                     u64* __restrict__ pairs,
                                                     u64* __restrict__ ovf,
                                                     u32* __restrict__ ovf_cnt,
                                                     int n4, u32 C) {
    __shared__ u32 hist[NBIN_PAD];   // counts, then staging cursor
    __shared__ u32 bme[NBIN_PAD];    // biased dest base; [1020..1023] = wave totals
    __shared__ u64 stage[SUB4 * 4];  // 32 KB

    int t = threadIdx.x;
    int lane = t & 63, wid = t >> 6;
    int b0 = blockIdx.x * SUB4;

    // issue loads first so HBM latency overlaps hist zeroing
    int4 iv[4]; float4 uv[4];
#pragma unroll
    for (int k = 0; k < 4; ++k) {
        int p = b0 + t + 256 * k;
        if (p < n4) { iv[k] = idx4[p]; uv[k] = upd4[p]; }
    }
    for (int i = t; i < NBIN_PAD; i += 256) hist[i] = 0;
    __syncthreads();

    // histogram
#pragma unroll
    for (int k = 0; k < 4; ++k) {
        int p = b0 + t + 256 * k;
        if (p < n4) {
            atomicAdd(&hist[((u32)iv[k].x) >> 7], 1u);
            atomicAdd(&hist[((u32)iv[k].y) >> 7], 1u);
            atomicAdd(&hist[((u32)iv[k].z) >> 7], 1u);
            atomicAdd(&hist[((u32)iv[k].w) >> 7], 1u);
        }
    }
    __syncthreads();

    // exclusive scan: thread t owns bins 4t..4t+3; wave shfl scan + wave totals
    u32 c0 = hist[4 * t + 0], c1 = hist[4 * t + 1];
    u32 c2 = hist[4 * t + 2], c3 = hist[4 * t + 3];
    u32 tsum = c0 + c1 + c2 + c3;
    u32 incl = tsum;
#pragma unroll
    for (int d = 1; d < 64; d <<= 1) {
        u32 y = __shfl_up(incl, (unsigned)d, 64);
        if (lane >= d) incl += y;
    }
    if (lane == 63) bme[1020 + wid] = incl;   // bins 1020..1023 are always empty
    __syncthreads();
    u32 woff = 0;
#pragma unroll
    for (int w = 0; w < 4; ++w) woff += (w < wid) ? bme[1020 + w] : 0u;
    u32 ebase = woff + incl - tsum;
    u32 e[4] = {ebase, ebase + c0, ebase + c0 + c1, ebase + c0 + c1 + c2};
    u32 cc[4] = {c0, c1, c2, c3};
#pragma unroll
    for (int j = 0; j < 4; ++j) {
        u32 bin = 4 * (u32)t + j;
        u32 c = cc[j];
        if (c) {
            u32 gb = atomicAdd(&cursor[bin], c);
            u32 lim = C ? (bin + 1u) * C : 0xFFFFFFFFu;
            u32 bm;
            if (gb + c > lim) {
                u32 ob = atomicAdd(ovf_cnt, c);
                bm = (ob - e[j] + 8192u) | 0x80000000u;
            } else {
                bm = gb - e[j] + 8192u;
            }
            bme[bin] = bm;
            hist[bin] = e[j];   // staging cursor starts at exclusive prefix
        }
    }
    __syncthreads();

    // stage bin-sorted
    u32 colbase = ((u32)t * 4u) & 255u;
#pragma unroll
    for (int k = 0; k < 4; ++k) {
        int p = b0 + t + 256 * k;
        if (p >= n4) continue;
        int rows[4] = {iv[k].x, iv[k].y, iv[k].z, iv[k].w};
        float vals[4] = {uv[k].x, uv[k].y, uv[k].z, uv[k].w};
#pragma unroll
        for (int c = 0; c < 4; ++c) {
            u32 row = (u32)rows[c];
            u32 slot = atomicAdd(&hist[row >> 7], 1u);
            stage[slot] = ((u64)__float_as_uint(vals[c]) << 32)
                        | ((u64)row << 8) | (u64)(colbase + (u32)c);
        }
    }
    __syncthreads();

    // coalesced flush
    int scount = 4 * (n4 - b0); if (scount > 4 * SUB4) scount = 4 * SUB4;
    for (int i = t; i < scount; i += 256) {
        u64 pr = stage[i];
        u32 rc  = (u32)pr & 0x1ffffffu;   // row<<8 | col
        u32 row = rc >> 8;
        u32 bin = row >> 7;
        u32 v = bme[bin];
        u32 d = (v & 0x7fffffffu) + (u32)i - 8192u;
        if (v & 0x80000000u) {
            if (d < OVF_CAP) ovf[d] = pr;   // full-key pair
        } else {
            u32 key = ((row & 127u) << 8) | (rc & 255u);
            pairs[d] = (pr & 0xffffffff00000000ull) | (u64)key;
        }
    }
}

// ---------------- apply: two blocks per bin (column halves) ----------------
#define APPLY_P(p) { u32 k_ = (u32)(p); \
    if (((k_ >> 7) & 1u) == half) \
        atomicAdd(&acc[((k_ >> 8) & 127u) * 128u + (k_ & 127u)], \
                  __uint_as_float((u32)((p) >> 32))); }

__global__ void __launch_bounds__(1024, 8) apply_half(const float4* __restrict__ self4,
                                                      const u64* __restrict__ pairs,
                                                      const u32* __restrict__ start,
                                                      const u32* __restrict__ endc,
                                                      float4* __restrict__ out4,
                                                      int nrows, u32 C) {
    __shared__ float acc[RB * 128];   // 64 KB
    int t = threadIdx.x;
    int bin = blockIdx.x >> 1;
    u32 half = blockIdx.x & 1u;
    float4* acc4 = (float4*)acc;
    for (int i = t; i < RB * 32; i += 1024) acc4[i] = make_float4(0.f, 0.f, 0.f, 0.f);
    __syncthreads();

    u32 s = start[bin], e = endc[bin];
    if (C) { u32 lim = ((u32)bin + 1u) * C; if (e > lim) e = lim; }
    u32 i = s + (u32)t;
    for (; i + 3072u < e; i += 4096u) {
        u64 p0 = pairs[i];
        u64 p1 = pairs[i + 1024u];
        u64 p2 = pairs[i + 2048u];
        u64 p3 = pairs[i + 3072u];
        APPLY_P(p0); APPLY_P(p1); APPLY_P(p2); APPLY_P(p3);
    }
    for (; i < e; i += 1024u) { u64 p0 = pairs[i]; APPLY_P(p0); }
    __syncthreads();

    int r0 = bin * RB;
    int nr = nrows - r0; if (nr > RB) nr = RB;
    int tot4 = nr * 32;
    for (int i2 = t; i2 < tot4; i2 += 1024) {
        int r = i2 >> 5, c4 = i2 & 31;
        long g = (long)(r0 + r) * 64 + (long)(half * 32u) + c4;
        float4 a = self4[g];
        float4 c = acc4[(r << 5) + c4];
        a.x += c.x; a.y += c.y; a.z += c.z; a.w += c.w;
        out4[g] = a;
    }
}

// ---------------- overflow fixup (capacity mode; normally 0 items) ----------------
__global__ void ovf_fixup(const u64* __restrict__ ovf, const u32* __restrict__ ovf_cnt,
                          float* __restrict__ out) {
    u32 n = *ovf_cnt; if (n > OVF_CAP) n = OVF_CAP;
    u32 i = blockIdx.x * blockDim.x + threadIdx.x;
    u32 stride = gridDim.x * blockDim.x;
    for (; i < n; i += stride) {
        u64 pr = ovf[i];
        u32 rc = (u32)pr & 0x1ffffffu;
        atomicAdd(&out[(rc >> 8) * 256u + (rc & 255u)], __uint_as_float((u32)(pr >> 32)));
    }
}

extern "C" void kernel_launch(void* const* d_in, const int* in_sizes, int n_in,
                              void* d_out, int out_size, void* d_ws, size_t ws_size,
                              hipStream_t stream) {
    const float* self_t = (const float*)d_in[0];   // N*D fp32
    const int*   index  = (const int*)d_in[1];     // M*D int32
    const float* upd    = (const float*)d_in[2];   // M*D fp32
    float* out = (float*)d_out;

    const int nd = out_size;      // N*D
    const int md = in_sizes[1];   // M*D
    const int nrows = nd / DCOLS;
    const int nbins = (nrows + RB - 1) / RB;
    int n4 = md / 4;

    u32* meta   = (u32*)d_ws;
    u32* count  = meta;
    u32* start  = meta + 1024;
    u32* cursor = meta + 2048;
    u32* ovf_cnt = meta + 3072;
    u64* pairs  = (u64*)((char*)d_ws + PAIRS_OFF);

    size_t need_cap   = (size_t)PAIRS_OFF + (size_t)nbins * CAPC * 8 + (size_t)OVF_CAP * 8;
    size_t need_exact = (size_t)PAIRS_OFF + (size_t)md * 8;
    bool shape_ok = (nbins <= NBIN_PAD) && !(md & 3) && !(nd & 3);
    int sblocks = (n4 + SUB4 - 1) / SUB4;

    if (shape_ok && ws_size >= need_cap) {
        // capacity mode: no count/scan prepass
        u64* ovf = pairs + (size_t)nbins * CAPC;
        zero_cap<<<1, 1024, 0, stream>>>(meta, CAPC);
        scatter_v4<<<sblocks, 256, 0, stream>>>((const int4*)index, (const float4*)upd,
                                                cursor, pairs, ovf, ovf_cnt, n4, CAPC);
        apply_half<<<2 * nbins, 1024, 0, stream>>>((const float4*)self_t, pairs, start,
                                                   cursor, (float4*)out, nrows, CAPC);
        ovf_fixup<<<64, 256, 0, stream>>>(ovf, ovf_cnt, out);
    } else if (shape_ok && ws_size >= need_exact) {
        // exact mode: count + scan then same scatter/apply (C=0 -> no overflow)
        zero_meta<<<1, 1024, 0, stream>>>(count, nbins);
        count_bins<<<1024, 256, 0, stream>>>((const int4*)index, count, n4);
        scan_bins<<<1, 1024, 0, stream>>>(count, start, cursor, nbins);
        scatter_v4<<<sblocks, 256, 0, stream>>>((const int4*)index, (const float4*)upd,
                                                cursor, pairs, pairs, ovf_cnt, n4, 0u);
        apply_half<<<2 * nbins, 1024, 0, stream>>>((const float4*)self_t, pairs, start,
                                                   cursor, (float4*)out, nrows, 0u);
    } else {
        copy_f4<<<2048, 256, 0, stream>>>((const float4*)self_t, (float4*)out, nd / 4);
        scatter_add4<<<4096, 256, 0, stream>>>((const int4*)index, (const float4*)upd, out, md / 4);
    }
}

// Round 6
// 241.917 us; speedup vs baseline: 1.4668x; 1.4668x over previous
//
#include <hip/hip_runtime.h>

#define DCOLS 256
#define RB 128             // rows per bin
#define PAIRS_OFF 16384    // byte offset of pairs[] in d_ws
#define CAPC 17152u        // pairs capacity per bin (mean 16368 + ~6 sigma)
#define OVF_CAP (1u<<20)   // overflow list capacity (pairs)

typedef unsigned int u32;
typedef unsigned long long u64;

// ---------------- fallback path ----------------
__global__ void copy_f4(const float4* __restrict__ src, float4* __restrict__ dst, int n4) {
    int i = blockIdx.x * blockDim.x + threadIdx.x;
    int stride = gridDim.x * blockDim.x;
    for (; i < n4; i += stride) dst[i] = src[i];
}

__global__ void scatter_add4(const int4* __restrict__ index,
                             const float4* __restrict__ upd,
                             float* __restrict__ out, int n4) {
    int i = blockIdx.x * blockDim.x + threadIdx.x;
    int stride = gridDim.x * blockDim.x;
    for (; i < n4; i += stride) {
        int4 idx  = index[i];
        float4 u  = upd[i];
        int j = (i << 2) & (DCOLS - 1);
        atomicAdd(&out[idx.x * DCOLS + j + 0], u.x);
        atomicAdd(&out[idx.y * DCOLS + j + 1], u.y);
        atomicAdd(&out[idx.z * DCOLS + j + 2], u.z);
        atomicAdd(&out[idx.w * DCOLS + j + 3], u.w);
    }
}

// ---------------- meta init (capacity mode) ----------------
__global__ void zero_cap(u32* __restrict__ meta, u32 C) {
    int t = threadIdx.x;
    meta[1024 + t] = (u32)t * C;   // start
    meta[2048 + t] = (u32)t * C;   // cursor
    if (t == 0) meta[3072] = 0;    // ovf_cnt
}

// ---------------- scatter v5: 16384 elements/block, 4 pipelined sub-chunks ----
// LDS: histp 8K (counts packed 2 subs/u32, then reused as staging cursors)
//      + bme 4K + bov 4K + stage 32K = 48KB -> 3 blocks/CU.
__global__ void __launch_bounds__(256, 3) scatter_v5(
        const int4* __restrict__ idx4, const float4* __restrict__ upd4,
        u32* __restrict__ cursor, u64* __restrict__ pairs,
        u64* __restrict__ ovf, u32* __restrict__ ovf_cnt, int n4, u32 C) {
    __shared__ u32 histp[2048];   // [s>>1][bin], halves = subs (s&1)
    __shared__ u32 bme[1024];     // gb - excl + 8192 per bin; [1020..1023] wave totals
    __shared__ u32 bov[1024];     // overflow dest bias (only set when chunk-bin overflows)
    __shared__ u64 stage[4096];   // 32 KB

    int t = threadIdx.x;
    int lane = t & 63, wid = t >> 6;
    int b0 = blockIdx.x * 4096;   // int4 units

    // sub-0 loads issued first (overlap with hist zeroing)
    int4 ivc[4]; float4 uvc[4];
#pragma unroll
    for (int k = 0; k < 4; ++k) {
        int p = b0 + t + 256 * k;
        if (p < n4) { ivc[k] = idx4[p]; uvc[k] = upd4[p]; }
    }
#pragma unroll
    for (int i = 0; i < 8; ++i) histp[t + 256 * i] = 0;
    __syncthreads();

    // phase A: per-sub histograms, packed
#pragma unroll
    for (int s = 0; s < 4; ++s) {
        u32 inc  = 1u << ((s & 1) * 16);
        u32 base = (u32)(s >> 1) * 1024u;
#pragma unroll
        for (int k = 0; k < 4; ++k) {
            int p = b0 + t + 256 * (4 * s + k);
            if (p < n4) {
                int4 v = (s == 0) ? ivc[k] : idx4[p];
                atomicAdd(&histp[base + (((u32)v.x) >> 7)], inc);
                atomicAdd(&histp[base + (((u32)v.y) >> 7)], inc);
                atomicAdd(&histp[base + (((u32)v.z) >> 7)], inc);
                atomicAdd(&histp[base + (((u32)v.w) >> 7)], inc);
            }
        }
    }
    __syncthreads();

    // one global reservation per chunk-bin (thread t owns bins 4t..4t+3)
    u32 gb[4]; u32 maxgl[4]; u32 gob[4]; bool ovfq[4];
#pragma unroll
    for (int j = 0; j < 4; ++j) {
        u32 b = 4u * (u32)t + (u32)j;
        u32 w0 = histp[b], w1 = histp[1024 + b];
        u32 tot = (w0 & 0xffffu) + (w0 >> 16) + (w1 & 0xffffu) + (w1 >> 16);
        gb[j] = 0; ovfq[j] = false; maxgl[j] = 0; gob[j] = 0;
        if (tot) {
            u32 g = atomicAdd(&cursor[b], tot);
            gb[j] = g;
            u32 lim = (b + 1u) * C;
            if (g + tot > lim) {                 // astronomically rare
                u32 mg = (g > lim) ? g : lim;
                gob[j] = atomicAdd(ovf_cnt, g + tot - mg);
                maxgl[j] = mg;
                ovfq[j] = true;
            }
        }
    }

    // phase B: 4 sub-chunks, loads pipelined one ahead
    int4 ivn[4]; float4 uvn[4];
    for (int s = 0; s < 4; ++s) {
        if (s < 3) {
#pragma unroll
            for (int k = 0; k < 4; ++k) {
                int p = b0 + t + 256 * (4 * (s + 1) + k);
                if (p < n4) { ivn[k] = idx4[p]; uvn[k] = upd4[p]; }
            }
        }
        u32 shift = (u32)(s & 1) * 16u;
        u32 base  = (u32)(s >> 1) * 1024u;
        u32 c[4];
#pragma unroll
        for (int j = 0; j < 4; ++j)
            c[j] = (histp[base + 4 * t + j] >> shift) & 0xffffu;
        u32 tsum = c[0] + c[1] + c[2] + c[3];
        u32 incl = tsum;
#pragma unroll
        for (int d = 1; d < 64; d <<= 1) {
            u32 y = __shfl_up(incl, (unsigned)d, 64);
            if (lane >= d) incl += y;
        }
        if (lane == 63) bme[1020 + wid] = incl;   // bins 1020..1023 always empty
        __syncthreads();                          // (1)
        u32 woff = 0;
#pragma unroll
        for (int w = 0; w < 4; ++w) woff += (w < wid) ? bme[1020 + w] : 0u;
        u32 e = woff + incl - tsum;
#pragma unroll
        for (int j = 0; j < 4; ++j) {
            u32 b = 4u * (u32)t + (u32)j;
            if (c[j]) {
                bme[b] = gb[j] - e + 8192u;
                if (ovfq[j]) bov[b] = gob[j] - maxgl[j] - e + 8192u;
                // set staging cursor (this sub's packed half) to excl prefix
                u32 w = histp[base + b];
                histp[base + b] = (w & ~(0xffffu << shift)) | (e << shift);
            }
            e += c[j];
        }
        __syncthreads();                          // (2)

        // stage bin-sorted
#pragma unroll
        for (int k = 0; k < 4; ++k) {
            int p = b0 + t + 256 * (4 * s + k);
            if (p >= n4) continue;
            int rows[4] = {ivc[k].x, ivc[k].y, ivc[k].z, ivc[k].w};
            float vals[4] = {uvc[k].x, uvc[k].y, uvc[k].z, uvc[k].w};
            u32 colbase = (4u * (u32)t) & 255u;   // (p*4+c)&255 == (4t+c)&255
#pragma unroll
            for (int cc = 0; cc < 4; ++cc) {
                u32 row = (u32)rows[cc];
                u32 old = atomicAdd(&histp[base + (row >> 7)], 1u << shift);
                u32 slot = (old >> shift) & 0xffffu;
                stage[slot] = ((u64)__float_as_uint(vals[cc]) << 32)
                            | ((u64)row << 8) | (u64)(colbase + (u32)cc);
            }
        }
        __syncthreads();                          // (3)

        // coalesced flush
        int sv = n4 - (b0 + 1024 * s); if (sv > 1024) sv = 1024; if (sv < 0) sv = 0;
        int scount = 4 * sv;
        for (int i = t; i < scount; i += 256) {
            u64 pr = stage[i];
            u32 rc  = (u32)pr & 0x1ffffffu;   // row<<8 | col
            u32 row = rc >> 8;
            u32 bin = row >> 7;
            u32 d = bme[bin] + (u32)i - 8192u;
            if (d < (bin + 1u) * C) {
                u32 key = ((row & 127u) << 8) | (rc & 255u);
                pairs[d] = (pr & 0xffffffff00000000ull) | (u64)key;
            } else {
                u32 od = bov[bin] + (u32)i - 8192u;
                if (od < OVF_CAP) ovf[od] = pr;
            }
        }
#pragma unroll
        for (int j = 0; j < 4; ++j) gb[j] += c[j];
        if (s < 3) {
#pragma unroll
            for (int k = 0; k < 4; ++k) { ivc[k] = ivn[k]; uvc[k] = uvn[k]; }
        }
        __syncthreads();                          // (4)
    }
}

// ---------------- apply: two blocks per bin (column halves) ----------------
#define APPLY_P(p) { u32 k_ = (u32)(p); \
    if (((k_ >> 7) & 1u) == half) \
        atomicAdd(&acc[((k_ >> 8) & 127u) * 128u + (k_ & 127u)], \
                  __uint_as_float((u32)((p) >> 32))); }

__global__ void __launch_bounds__(1024, 8) apply_half(const float4* __restrict__ self4,
                                                      const u64* __restrict__ pairs,
                                                      const u32* __restrict__ start,
                                                      const u32* __restrict__ endc,
                                                      float4* __restrict__ out4,
                                                      int nrows, u32 C) {
    __shared__ float acc[RB * 128];   // 64 KB
    int t = threadIdx.x;
    int bin = blockIdx.x >> 1;
    u32 half = blockIdx.x & 1u;
    float4* acc4 = (float4*)acc;
    for (int i = t; i < RB * 32; i += 1024) acc4[i] = make_float4(0.f, 0.f, 0.f, 0.f);
    __syncthreads();

    u32 s = start[bin], e = endc[bin];
    u32 lim = ((u32)bin + 1u) * C;
    if (e > lim) e = lim;
    u32 i = s + (u32)t;
    for (; i + 3072u < e; i += 4096u) {
        u64 p0 = pairs[i];
        u64 p1 = pairs[i + 1024u];
        u64 p2 = pairs[i + 2048u];
        u64 p3 = pairs[i + 3072u];
        APPLY_P(p0); APPLY_P(p1); APPLY_P(p2); APPLY_P(p3);
    }
    for (; i < e; i += 1024u) { u64 p0 = pairs[i]; APPLY_P(p0); }
    __syncthreads();

    int r0 = bin * RB;
    int nr = nrows - r0; if (nr > RB) nr = RB;
    int tot4 = nr * 32;
    for (int i2 = t; i2 < tot4; i2 += 1024) {
        int r = i2 >> 5, c4 = i2 & 31;
        long g = (long)(r0 + r) * 64 + (long)(half * 32u) + c4;
        float4 a = self4[g];
        float4 c = acc4[(r << 5) + c4];
        a.x += c.x; a.y += c.y; a.z += c.z; a.w += c.w;
        out4[g] = a;
    }
}

// ---------------- overflow fixup (normally 0 items) ----------------
__global__ void ovf_fixup(const u64* __restrict__ ovf, const u32* __restrict__ ovf_cnt,
                          float* __restrict__ out) {
    u32 n = *ovf_cnt; if (n > OVF_CAP) n = OVF_CAP;
    u32 i = blockIdx.x * blockDim.x + threadIdx.x;
    u32 stride = gridDim.x * blockDim.x;
    for (; i < n; i += stride) {
        u64 pr = ovf[i];
        u32 rc = (u32)pr & 0x1ffffffu;
        atomicAdd(&out[(rc >> 8) * 256u + (rc & 255u)], __uint_as_float((u32)(pr >> 32)));
    }
}

extern "C" void kernel_launch(void* const* d_in, const int* in_sizes, int n_in,
                              void* d_out, int out_size, void* d_ws, size_t ws_size,
                              hipStream_t stream) {
    const float* self_t = (const float*)d_in[0];   // N*D fp32
    const int*   index  = (const int*)d_in[1];     // M*D int32
    const float* upd    = (const float*)d_in[2];   // M*D fp32
    float* out = (float*)d_out;

    const int nd = out_size;      // N*D
    const int md = in_sizes[1];   // M*D
    const int nrows = nd / DCOLS;
    const int nbins = (nrows + RB - 1) / RB;
    int n4 = md / 4;

    u32* meta    = (u32*)d_ws;
    u32* start   = meta + 1024;
    u32* cursor  = meta + 2048;
    u32* ovf_cnt = meta + 3072;
    u64* pairs   = (u64*)((char*)d_ws + PAIRS_OFF);

    size_t need_cap = (size_t)PAIRS_OFF + (size_t)nbins * CAPC * 8 + (size_t)OVF_CAP * 8;
    bool shape_ok = (nbins <= 1020) && !(md & 3) && !(nd & 3) &&
                    (md % DCOLS == 0) && (nd % DCOLS == 0);

    if (shape_ok && ws_size >= need_cap) {
        u64* ovf = pairs + (size_t)nbins * CAPC;
        int sblocks = (n4 + 4095) / 4096;
        zero_cap<<<1, 1024, 0, stream>>>(meta, CAPC);
        scatter_v5<<<sblocks, 256, 0, stream>>>((const int4*)index, (const float4*)upd,
                                                cursor, pairs, ovf, ovf_cnt, n4, CAPC);
        apply_half<<<2 * nbins, 1024, 0, stream>>>((const float4*)self_t, pairs, start,
                                                   cursor, (float4*)out, nrows, CAPC);
        ovf_fixup<<<64, 256, 0, stream>>>(ovf, ovf_cnt, out);
    } else {
        copy_f4<<<2048, 256, 0, stream>>>((const float4*)self_t, (float4*)out, nd / 4);
        scatter_add4<<<4096, 256, 0, stream>>>((const int4*)index, (const float4*)upd, out, md / 4);
    }
}

// Round 7
// 204.134 us; speedup vs baseline: 1.7383x; 1.1851x over previous
//
#include <hip/hip_runtime.h>

#define DCOLS 256
#define RB 128               // rows per bin
#define NBINP 1024           // padded bin count (actual 782)
#define MAT_OFF 16384        // per-(block,bin) count/offset matrix
#define MAT_CAP (4u<<20)     // 4 MB reserved for matrix (nblk <= 1024)
#define PAIRS_OFF (MAT_OFF + MAT_CAP)
#define BLK4 1024            // int4 per sub-chunk (4096 elements)
#define SUBS 4
#define CHUNK4 (BLK4 * SUBS) // 4096 int4 = 16384 elements per scatter block

typedef unsigned int u32;
typedef unsigned short u16;
typedef unsigned long long u64;

// ---------------- fallback path ----------------
__global__ void copy_f4(const float4* __restrict__ src, float4* __restrict__ dst, int n4) {
    int i = blockIdx.x * blockDim.x + threadIdx.x;
    int stride = gridDim.x * blockDim.x;
    for (; i < n4; i += stride) dst[i] = src[i];
}

__global__ void scatter_add4(const int4* __restrict__ index,
                             const float4* __restrict__ upd,
                             float* __restrict__ out, int n4) {
    int i = blockIdx.x * blockDim.x + threadIdx.x;
    int stride = gridDim.x * blockDim.x;
    for (; i < n4; i += stride) {
        int4 idx  = index[i];
        float4 u  = upd[i];
        int j = (i << 2) & (DCOLS - 1);
        atomicAdd(&out[idx.x * DCOLS + j + 0], u.x);
        atomicAdd(&out[idx.y * DCOLS + j + 1], u.y);
        atomicAdd(&out[idx.z * DCOLS + j + 2], u.z);
        atomicAdd(&out[idx.w * DCOLS + j + 3], u.w);
    }
}

// ---------------- K1: per-block histogram -> mat[blk][bin] (no global atomics) ----
__global__ void __launch_bounds__(256) hist_blocks(const int4* __restrict__ idx4,
                                                   u32* __restrict__ mat, int n4) {
    __shared__ u32 hist[NBINP];
    int t = threadIdx.x;
    int b0 = blockIdx.x * CHUNK4;
    for (int i = t; i < NBINP; i += 256) hist[i] = 0;
    __syncthreads();
#pragma unroll
    for (int k = 0; k < 16; ++k) {
        int p = b0 + t + 256 * k;
        if (p < n4) {
            int4 v = idx4[p];
            atomicAdd(&hist[((u32)v.x) >> 7], 1u);
            atomicAdd(&hist[((u32)v.y) >> 7], 1u);
            atomicAdd(&hist[((u32)v.z) >> 7], 1u);
            atomicAdd(&hist[((u32)v.w) >> 7], 1u);
        }
    }
    __syncthreads();
    u32 base = (u32)blockIdx.x * NBINP;
    for (int i = t; i < NBINP; i += 256) mat[base + i] = hist[i];
}

// ---------------- K2: one wave per bin, exclusive scan over blocks --------------
__global__ void __launch_bounds__(64) scan_blocks(u32* __restrict__ mat,
                                                  u32* __restrict__ total, int nblk) {
    int bin = blockIdx.x;
    int lane = threadIdx.x;
    u32 carry = 0;
    int rounds = (nblk + 63) / 64;
    for (int r = 0; r < rounds; ++r) {
        int blk = r * 64 + lane;
        u32 v = (blk < nblk) ? mat[(u32)blk * NBINP + bin] : 0u;
        u32 incl = v;
#pragma unroll
        for (int d = 1; d < 64; d <<= 1) {
            u32 y = __shfl_up(incl, (unsigned)d, 64);
            if (lane >= d) incl += y;
        }
        if (blk < nblk) mat[(u32)blk * NBINP + bin] = carry + incl - v;  // exclusive
        carry += (u32)__shfl(incl, 63, 64);
    }
    if (lane == 0) total[bin] = carry;
}

// ---------------- K2b: exclusive scan of bin totals -> bin bases ---------------
__global__ void scan_binbases(const u32* __restrict__ total, u32* __restrict__ start) {
    __shared__ u32 tmp[1024];
    int t = threadIdx.x;
    u32 v = total[t];
    tmp[t] = v;
    __syncthreads();
    for (int off = 1; off < 1024; off <<= 1) {
        u32 a = (t >= off) ? tmp[t - off] : 0u;
        __syncthreads();
        tmp[t] += a;
        __syncthreads();
    }
    start[t] = tmp[t] - v;
}

// ---------------- K3: scatter with deterministic destinations (no atomics) -----
// LDS = hist 4K + basep 4K + excl16 2K + wtot + stage 32K ~= 42.3 KB -> 3 blocks/CU
__global__ void __launch_bounds__(256, 3) scatter_det(const int4* __restrict__ idx4,
                                                      const float4* __restrict__ upd4,
                                                      const u32* __restrict__ mat,
                                                      const u32* __restrict__ start,
                                                      u64* __restrict__ pairs, int n4) {
    __shared__ u32 hist[NBINP];     // per-sub counts, then staging cursors
    __shared__ u32 basep[NBINP];    // absolute dest base per bin (advances per sub)
    __shared__ u16 excl16[NBINP];   // per-sub exclusive prefix within stage
    __shared__ u32 wtot[4];
    __shared__ u64 stage[4096];     // 32 KB

    int t = threadIdx.x;
    int lane = t & 63, wid = t >> 6;
    int b0 = blockIdx.x * CHUNK4;
    u32 mbase = (u32)blockIdx.x * NBINP;

    for (int i = t; i < NBINP; i += 256) basep[i] = start[i] + mat[mbase + i];
    // (first cross-thread read of basep happens after several barriers below)

    for (int s = 0; s < SUBS; ++s) {
        int sbase = b0 + s * BLK4;
        int4 iv[4]; float4 uv[4];
#pragma unroll
        for (int k = 0; k < 4; ++k) {
            int p = sbase + t + 256 * k;
            if (p < n4) { iv[k] = idx4[p]; uv[k] = upd4[p]; }
        }
        for (int i = t; i < NBINP; i += 256) hist[i] = 0;
        __syncthreads();
#pragma unroll
        for (int k = 0; k < 4; ++k) {
            int p = sbase + t + 256 * k;
            if (p < n4) {
                atomicAdd(&hist[((u32)iv[k].x) >> 7], 1u);
                atomicAdd(&hist[((u32)iv[k].y) >> 7], 1u);
                atomicAdd(&hist[((u32)iv[k].z) >> 7], 1u);
                atomicAdd(&hist[((u32)iv[k].w) >> 7], 1u);
            }
        }
        __syncthreads();
        // exclusive scan of sub counts: thread t owns bins 4t..4t+3
        u32 c0 = hist[4 * t + 0], c1 = hist[4 * t + 1];
        u32 c2 = hist[4 * t + 2], c3 = hist[4 * t + 3];
        u32 tsum = c0 + c1 + c2 + c3;
        u32 incl = tsum;
#pragma unroll
        for (int d = 1; d < 64; d <<= 1) {
            u32 y = __shfl_up(incl, (unsigned)d, 64);
            if (lane >= d) incl += y;
        }
        if (lane == 63) wtot[wid] = incl;
        __syncthreads();
        u32 woff = 0;
#pragma unroll
        for (int w = 0; w < 4; ++w) woff += (w < wid) ? wtot[w] : 0u;
        u32 e0 = woff + incl - tsum;
        u32 e1 = e0 + c0, e2 = e1 + c1, e3 = e2 + c2;
        excl16[4 * t + 0] = (u16)e0; excl16[4 * t + 1] = (u16)e1;
        excl16[4 * t + 2] = (u16)e2; excl16[4 * t + 3] = (u16)e3;
        hist[4 * t + 0] = e0; hist[4 * t + 1] = e1;   // staging cursors
        hist[4 * t + 2] = e2; hist[4 * t + 3] = e3;
        __syncthreads();
        // stage bin-sorted
        u32 colbase = (4u * (u32)t) & 255u;
#pragma unroll
        for (int k = 0; k < 4; ++k) {
            int p = sbase + t + 256 * k;
            if (p >= n4) continue;
            int rows[4] = {iv[k].x, iv[k].y, iv[k].z, iv[k].w};
            float vals[4] = {uv[k].x, uv[k].y, uv[k].z, uv[k].w};
#pragma unroll
            for (int c = 0; c < 4; ++c) {
                u32 row = (u32)rows[c];
                u32 slot = atomicAdd(&hist[row >> 7], 1u);
                stage[slot] = ((u64)__float_as_uint(vals[c]) << 32)
                            | ((u64)row << 8) | (u64)(colbase + (u32)c);
            }
        }
        __syncthreads();
        // coalesced flush to exact destinations
        int sv = n4 - sbase; if (sv > BLK4) sv = BLK4; if (sv < 0) sv = 0;
        int scount = 4 * sv;
        for (int i = t; i < scount; i += 256) {
            u64 pr = stage[i];
            u32 rc  = (u32)pr & 0x1ffffffu;   // row<<8 | col
            u32 row = rc >> 8;
            u32 bin = row >> 7;
            u32 d = basep[bin] + ((u32)i - (u32)excl16[bin]);
            u32 key = ((row & 127u) << 8) | (rc & 255u);
            pairs[d] = (pr & 0xffffffff00000000ull) | (u64)key;
        }
        __syncthreads();
        // advance bases by this sub's per-bin counts (hist = end cursor)
        for (int b = t; b < NBINP; b += 256) basep[b] += hist[b] - (u32)excl16[b];
        __syncthreads();
    }
}

// ---------------- K4: apply, two blocks per bin (column halves) ----------------
#define APPLY_P(p) { u32 k_ = (u32)(p); \
    if (((k_ >> 7) & 1u) == half) \
        atomicAdd(&acc[((k_ >> 8) & 127u) * 128u + (k_ & 127u)], \
                  __uint_as_float((u32)((p) >> 32))); }

__global__ void __launch_bounds__(1024, 8) apply_half(const float4* __restrict__ self4,
                                                      const u64* __restrict__ pairs,
                                                      const u32* __restrict__ start,
                                                      const u32* __restrict__ total,
                                                      float4* __restrict__ out4, int nrows) {
    __shared__ float acc[RB * 128];   // 64 KB
    int t = threadIdx.x;
    int bin = blockIdx.x >> 1;
    u32 half = blockIdx.x & 1u;
    float4* acc4 = (float4*)acc;
    for (int i = t; i < RB * 32; i += 1024) acc4[i] = make_float4(0.f, 0.f, 0.f, 0.f);
    __syncthreads();

    u32 s = start[bin], e = s + total[bin];
    u32 i = s + (u32)t;
    for (; i + 3072u < e; i += 4096u) {
        u64 p0 = pairs[i];
        u64 p1 = pairs[i + 1024u];
        u64 p2 = pairs[i + 2048u];
        u64 p3 = pairs[i + 3072u];
        APPLY_P(p0); APPLY_P(p1); APPLY_P(p2); APPLY_P(p3);
    }
    for (; i < e; i += 1024u) { u64 p0 = pairs[i]; APPLY_P(p0); }
    __syncthreads();

    int r0 = bin * RB;
    int nr = nrows - r0; if (nr > RB) nr = RB;
    int tot4 = nr * 32;
    for (int i2 = t; i2 < tot4; i2 += 1024) {
        int r = i2 >> 5, c4 = i2 & 31;
        long g = (long)(r0 + r) * 64 + (long)(half * 32u) + c4;
        float4 a = self4[g];
        float4 c = acc4[(r << 5) + c4];
        a.x += c.x; a.y += c.y; a.z += c.z; a.w += c.w;
        out4[g] = a;
    }
}

extern "C" void kernel_launch(void* const* d_in, const int* in_sizes, int n_in,
                              void* d_out, int out_size, void* d_ws, size_t ws_size,
                              hipStream_t stream) {
    const float* self_t = (const float*)d_in[0];   // N*D fp32
    const int*   index  = (const int*)d_in[1];     // M*D int32
    const float* upd    = (const float*)d_in[2];   // M*D fp32
    float* out = (float*)d_out;

    const int nd = out_size;      // N*D
    const int md = in_sizes[1];   // M*D
    const int nrows = nd / DCOLS;
    const int nbins = (nrows + RB - 1) / RB;
    int n4 = md / 4;
    int nblk = (n4 + CHUNK4 - 1) / CHUNK4;

    u32* total = (u32*)d_ws;                       // 1024 u32
    u32* start = total + 1024;                     // 1024 u32
    u32* mat   = (u32*)((char*)d_ws + MAT_OFF);    // nblk*1024 u32
    u64* pairs = (u64*)((char*)d_ws + PAIRS_OFF);  // md pairs

    size_t need = (size_t)PAIRS_OFF + (size_t)md * 8;
    bool shape_ok = (nbins <= NBINP) && (nblk <= 1024) && !(md & 3) && !(nd & 3) &&
                    (md % DCOLS == 0) && (nd % DCOLS == 0);

    if (shape_ok && ws_size >= need) {
        hist_blocks<<<nblk, 256, 0, stream>>>((const int4*)index, mat, n4);
        scan_blocks<<<NBINP, 64, 0, stream>>>(mat, total, nblk);
        scan_binbases<<<1, 1024, 0, stream>>>(total, start);
        scatter_det<<<nblk, 256, 0, stream>>>((const int4*)index, (const float4*)upd,
                                              mat, start, pairs, n4);
        apply_half<<<2 * nbins, 1024, 0, stream>>>((const float4*)self_t, pairs, start,
                                                   total, (float4*)out, nrows);
    } else {
        copy_f4<<<2048, 256, 0, stream>>>((const float4*)self_t, (float4*)out, nd / 4);
        scatter_add4<<<4096, 256, 0, stream>>>((const int4*)index, (const float4*)upd, out, md / 4);
    }
}